// Round 3
// baseline (1619.211 us; speedup 1.0000x reference)
//
#include <hip/hip_runtime.h>
#include <hip/hip_cooperative_groups.h>

namespace cg = cooperative_groups;

#define T_TOTAL 65536
#define SEQ 128
#define DMODEL 512
#define DHEAD 64
#define NTYPES 10000
#define ROWS 8192
#define NOUT_PAD 10240  // 40*256
#define NBLOCKS 256
#define NTHREADS 512
#define SH_BYTES 132096

typedef float floatx4 __attribute__((ext_vector_type(4)));
typedef short shortx8 __attribute__((ext_vector_type(8)));

#define GLOAD_LDS(gp, lp) __builtin_amdgcn_global_load_lds( \
    (const __attribute__((address_space(1))) void*)(gp),    \
    (__attribute__((address_space(3))) void*)(lp), 16, 0, 0)

#define MFMA_BF16 __builtin_amdgcn_mfma_f32_16x16x32_bf16

__device__ __forceinline__ unsigned short f2bf(float f) {
  union { float f; unsigned u; } v; v.f = f;
  unsigned u = v.u + 0x7fffu + ((v.u >> 16) & 1u);
  return (unsigned short)(u >> 16);
}

__device__ __forceinline__ void phase_barrier() {
  __builtin_amdgcn_sched_barrier(0);
  __builtin_amdgcn_s_barrier();
  __builtin_amdgcn_sched_barrier(0);
}

struct MegaParams {
  const int* item_ids; const int* seg_ids;
  const float* emb;
  const float* bqkv; const float* bo; const float* b1; const float* b2;
  const float* ln1s; const float* ln1b; const float* ln2s; const float* ln2b;
  const float* bout;
  const float* Wqkv; const float* Wo; const float* W1; const float* W2; const float* Wout;
  float* out;
  float* x_f; unsigned short* x_b; float* qkv_f; unsigned short* o_b;
  float* tmp_f; unsigned short* h_b;
  unsigned short* wqkv_b; unsigned short* wo_b; unsigned short* w1_b;
  unsigned short* w2_b; unsigned short* wout_b;
};

// ---------------- stage: f32 -> bf16 weight converts (grid-stride) ---------
__device__ __forceinline__ void dev_converts(const MegaParams& P) {
  // quad-element (float4) granularity; compile-time range table
  const long Q0 = 1572864L / 4;           // Wqkv
  const long Q1 = Q0 + 524288L / 4;       // Wo
  const long Q2 = Q1 + 1048576L / 4;      // W1
  const long Q3 = Q2 + 1048576L / 4;      // W2
  const long Q4 = Q3 + 5242880L / 4;      // Wout (padded dst)
  const long stride = (long)NBLOCKS * NTHREADS;
  for (long q = (long)blockIdx.x * NTHREADS + threadIdx.x; q < Q4; q += stride) {
    const float* src; unsigned short* dst; long i; bool guard = false;
    if (q < Q0)      { src = P.Wqkv; dst = P.wqkv_b; i = q; }
    else if (q < Q1) { src = P.Wo;   dst = P.wo_b;   i = q - Q0; }
    else if (q < Q2) { src = P.W1;   dst = P.w1_b;   i = q - Q1; }
    else if (q < Q3) { src = P.W2;   dst = P.w2_b;   i = q - Q2; }
    else             { src = P.Wout; dst = P.wout_b; i = q - Q3; guard = true; }
    long e = i * 4;
    float4 v = make_float4(0.f, 0.f, 0.f, 0.f);
    if (!guard || e < 5120000L) v = *(const float4*)(src + e);
    ushort4 o;
    o.x = f2bf(v.x); o.y = f2bf(v.y); o.z = f2bf(v.z); o.w = f2bf(v.w);
    *(ushort4*)(dst + e) = o;
  }
}

// ---------------- stage: segment-mean embedding + positional encoding ------
__device__ __forceinline__ void dev_seg_mean(const MegaParams& P) {
  int g = threadIdx.x >> 7;       // 0..3 segment group
  int t128 = threadIdx.x & 127;
  int c = t128 << 2;
#pragma unroll
  for (int it = 0; it < 8; ++it) {
    int s = blockIdx.x * 32 + it * 4 + g;   // 256*32 = 8192 exact
    int lo = 0, hi = T_TOTAL;
    while (lo < hi) { int mid = (lo + hi) >> 1; if (P.seg_ids[mid] < s) lo = mid + 1; else hi = mid; }
    int start = lo;
    hi = T_TOTAL;
    while (lo < hi) { int mid = (lo + hi) >> 1; if (P.seg_ids[mid] <= s) lo = mid + 1; else hi = mid; }
    int end = lo;
    float4 acc = make_float4(0.f, 0.f, 0.f, 0.f);
    for (int j = start; j < end; ++j) {
      const float* e = P.emb + (long)P.item_ids[j] * DMODEL + c;
      float4 v = *(const float4*)e;
      acc.x += v.x; acc.y += v.y; acc.z += v.z; acc.w += v.w;
    }
    int cnt = end - start;
    float inv = cnt > 0 ? 1.0f / (float)cnt : 0.0f;
    float mv[4] = {acc.x * inv, acc.y * inv, acc.z * inv, acc.w * inv};
    int l = s & (SEQ - 1);
    const float klog = 0.017988946039015984f;  // ln(10000)/512
    long base = (long)s * DMODEL + c;
#pragma unroll
    for (int t = 0; t < 4; ++t) {
      int col = c + t;
      float den = expf(-(float)(col & ~1) * klog);
      float ang = (float)l * den;
      float pe = (col & 1) ? cosf(ang) : sinf(ang);
      float val = mv[t] + pe;
      P.x_f[base + t] = val;
      P.x_b[base + t] = f2bf(val);
    }
  }
}

// ---------------- stage: 256x256 8-wave 4-phase bf16 MFMA GEMM -------------
// whole-block tile units; idle blocks skip (barriers are block-local).
// Stage issues front-loaded into phases 0-1 so the phase-3 vmcnt(0) drain
// sees loads issued >= 2 compute-phases earlier.
__device__ __forceinline__ void dev_gemm(char* sh,
    const unsigned short* __restrict__ A, const unsigned short* __restrict__ B,
    const float* __restrict__ bias, float* __restrict__ Cf,
    unsigned short* __restrict__ Cb, int K, int Nreal, int ldC, int relu,
    int tilesX, int tilesY) {
  unsigned short* AsBase = (unsigned short*)sh;            // [2][16384]
  unsigned short* BsBase = (unsigned short*)(sh + 65536);  // [2][16384]
  const int tid = threadIdx.x;
  const int lane = tid & 63;
  const int wave = tid >> 6;       // 0..7
  const int wm = wave >> 2;        // 0..1
  const int wn = wave & 3;         // 0..3
  const int l16 = lane & 15;
  const int quad = lane >> 4;
  const int srow = tid >> 3;
  const int scol = (tid & 7) << 3;
  const int loff = tid * 8;
  const long rstep = 64 * (long)K;
  const int nt = tilesX * tilesY;
  const int KT = K >> 6;

  for (int t = blockIdx.x; t < nt; t += NBLOCKS) {
    int tbx = t % tilesX, tby = t / tilesX;
    long rowA0 = (long)tbx * 256;
    long rowB0 = (long)tby * 256;
    floatx4 acc[8][4] = {};
    const unsigned short* gA = A + (rowA0 + srow) * (long)K + scol;
    const unsigned short* gB = B + (rowB0 + srow) * (long)K + scol;

    // prologue: K-tile 0 into buffer 0
#pragma unroll
    for (int is = 0; is < 4; ++is) {
      GLOAD_LDS(gA + is * rstep, AsBase + is * 4096 + loff);
      GLOAD_LDS(gB + is * rstep, BsBase + is * 4096 + loff);
    }
    asm volatile("s_waitcnt vmcnt(0)" ::: "memory");
    phase_barrier();

    for (int kt = 0; kt < KT; ++kt) {
      const int cur = kt & 1;
      const unsigned short* Ab = AsBase + cur * 16384;
      const unsigned short* Bb = BsBase + cur * 16384;
      unsigned short* An = AsBase + (cur ^ 1) * 16384;
      unsigned short* Bn = BsBase + (cur ^ 1) * 16384;
      const bool stage = (kt + 1) < KT;
      const unsigned short* gAn = gA + (long)(kt + 1) * 64;
      const unsigned short* gBn = gB + (long)(kt + 1) * 64;

      shortx8 af[4][2], bf[4][2];

      // ---- phase 0: reads af(m0-3) + bf(n0-1); stage ALL A halves ----
#pragma unroll
      for (int m = 0; m < 4; ++m) {
        const unsigned short* p = Ab + (wm * 128 + m * 16 + l16) * 64 + quad * 8;
        af[m][0] = *(const shortx8*)(p);
        af[m][1] = *(const shortx8*)(p + 32);
      }
#pragma unroll
      for (int n = 0; n < 2; ++n) {
        const unsigned short* p = Bb + (wn * 64 + n * 16 + l16) * 64 + quad * 8;
        bf[n][0] = *(const shortx8*)(p);
        bf[n][1] = *(const shortx8*)(p + 32);
      }
      if (stage) {
        GLOAD_LDS(gAn, An + loff);
        GLOAD_LDS(gAn + rstep, An + 4096 + loff);
        GLOAD_LDS(gAn + 2 * rstep, An + 8192 + loff);
        GLOAD_LDS(gAn + 3 * rstep, An + 12288 + loff);
      }
      phase_barrier();
      __builtin_amdgcn_s_setprio(1);
#pragma unroll
      for (int m = 0; m < 4; ++m)
#pragma unroll
        for (int n = 0; n < 2; ++n) {
          acc[m][n] = MFMA_BF16(af[m][0], bf[n][0], acc[m][n], 0, 0, 0);
          acc[m][n] = MFMA_BF16(af[m][1], bf[n][1], acc[m][n], 0, 0, 0);
        }
      __builtin_amdgcn_s_setprio(0);
      phase_barrier();

      // ---- phase 1: reads bf(n2-3); stage ALL B halves ----
#pragma unroll
      for (int n = 2; n < 4; ++n) {
        const unsigned short* p = Bb + (wn * 64 + n * 16 + l16) * 64 + quad * 8;
        bf[n][0] = *(const shortx8*)(p);
        bf[n][1] = *(const shortx8*)(p + 32);
      }
      if (stage) {
        GLOAD_LDS(gBn, Bn + loff);
        GLOAD_LDS(gBn + rstep, Bn + 4096 + loff);
        GLOAD_LDS(gBn + 2 * rstep, Bn + 8192 + loff);
        GLOAD_LDS(gBn + 3 * rstep, Bn + 12288 + loff);
      }
      phase_barrier();
      __builtin_amdgcn_s_setprio(1);
#pragma unroll
      for (int m = 0; m < 4; ++m)
#pragma unroll
        for (int n = 2; n < 4; ++n) {
          acc[m][n] = MFMA_BF16(af[m][0], bf[n][0], acc[m][n], 0, 0, 0);
          acc[m][n] = MFMA_BF16(af[m][1], bf[n][1], acc[m][n], 0, 0, 0);
        }
      __builtin_amdgcn_s_setprio(0);
      phase_barrier();

      // ---- phase 2: reads af(m4-7); MFMA m4-7 x n0-1 ----
#pragma unroll
      for (int m = 0; m < 4; ++m) {
        const unsigned short* p = Ab + (wm * 128 + 64 + m * 16 + l16) * 64 + quad * 8;
        af[m][0] = *(const shortx8*)(p);
        af[m][1] = *(const shortx8*)(p + 32);
      }
      phase_barrier();
      __builtin_amdgcn_s_setprio(1);
#pragma unroll
      for (int m = 0; m < 4; ++m)
#pragma unroll
        for (int n = 0; n < 2; ++n) {
          acc[4 + m][n] = MFMA_BF16(af[m][0], bf[n][0], acc[4 + m][n], 0, 0, 0);
          acc[4 + m][n] = MFMA_BF16(af[m][1], bf[n][1], acc[4 + m][n], 0, 0, 0);
        }
      __builtin_amdgcn_s_setprio(0);
      phase_barrier();

      // ---- phase 3: MFMA m4-7 x n2-3; tile-end drain ----
      __builtin_amdgcn_s_setprio(1);
#pragma unroll
      for (int m = 0; m < 4; ++m)
#pragma unroll
        for (int n = 2; n < 4; ++n) {
          acc[4 + m][n] = MFMA_BF16(af[m][0], bf[n][0], acc[4 + m][n], 0, 0, 0);
          acc[4 + m][n] = MFMA_BF16(af[m][1], bf[n][1], acc[4 + m][n], 0, 0, 0);
        }
      __builtin_amdgcn_s_setprio(0);
      asm volatile("s_waitcnt vmcnt(0)" ::: "memory");
      phase_barrier();
    }

    // epilogue (registers only)
#pragma unroll
    for (int m = 0; m < 8; ++m) {
      int row = (int)rowA0 + wm * 128 + m * 16 + quad * 4;
#pragma unroll
      for (int n = 0; n < 4; ++n) {
        int col = (int)rowB0 + wn * 64 + n * 16 + l16;
        if (col < Nreal) {
          float bv = bias ? bias[col] : 0.0f;
#pragma unroll
          for (int r = 0; r < 4; ++r) {
            float v = acc[m][n][r] + bv;
            if (relu) v = fmaxf(v, 0.0f);
            long off = (long)(row + r) * ldC + col;
            if (Cf) Cf[off] = v;
            if (Cb) Cb[off] = f2bf(v);
          }
        }
      }
    }
  }
}

// ---------------- stage: attention, 2 (b,h) pairs per block ----------------
__device__ __forceinline__ void dev_attn(char* sh, const float* __restrict__ qkv,
                                         unsigned short* __restrict__ o_b) {
  const int ph = threadIdx.x >> 8;       // 0/1 pair-half
  const int t256 = threadIdx.x & 255;
  float* Ks = (float*)sh + ph * 8192;
  float* Vs = (float*)(sh + 65536) + ph * 8192;
  float* Ds = (float*)(sh + 131072) + ph * 128;
  int p = blockIdx.x * 2 + ph;           // 0..511 exact
  int b = p >> 3, h = p & 7;
  const float* base = qkv + (long)b * SEQ * 1536;
  int hoff = h * DHEAD;
  for (int idx = t256; idx < SEQ * DHEAD; idx += 256) {
    int l = idx >> 6, c = idx & 63;
    Ks[idx] = base[l * 1536 + 512 + hoff + c];
    Vs[idx] = base[l * 1536 + 1024 + hoff + c];
  }
  __syncthreads();
  int l = t256 & 127;
  int half = t256 >> 7;
  float q[DHEAD];
#pragma unroll
  for (int c = 0; c < DHEAD; ++c) q[c] = base[l * 1536 + hoff + c];
  float o[DHEAD];
#pragma unroll
  for (int c = 0; c < DHEAD; ++c) o[c] = 0.f;
  float denom = 0.f;
  for (int j = half; j <= l; j += 2) {   // causal; parity split balances halves
    const float* kr = Ks + j * DHEAD;
    float s0 = 0.f, s1 = 0.f, s2 = 0.f, s3 = 0.f;
#pragma unroll
    for (int c = 0; c < DHEAD; c += 4) {
      s0 += q[c] * kr[c];         s1 += q[c + 1] * kr[c + 1];
      s2 += q[c + 2] * kr[c + 2]; s3 += q[c + 3] * kr[c + 3];
    }
    float pv = __expf(((s0 + s1) + (s2 + s3)) * 0.125f);  // 1/sqrt(64)
    denom += pv;
    const float* vr = Vs + j * DHEAD;
#pragma unroll
    for (int c = 0; c < DHEAD; ++c) o[c] += pv * vr[c];
  }
  __syncthreads();            // K no longer needed; reuse Ks for partials
  if (half) {
    float* os = Ks + l * DHEAD;
#pragma unroll
    for (int c = 0; c < DHEAD; ++c) os[c] = o[c];
    Ds[l] = denom;
  }
  __syncthreads();
  if (!half) {
    float dtot = denom + Ds[l];
    float inv = 1.0f / dtot;
    const float* os = Ks + l * DHEAD;
    unsigned short* dst = o_b + ((long)b * SEQ + l) * DMODEL + hoff;
#pragma unroll
    for (int c = 0; c < DHEAD; ++c) dst[c] = f2bf((o[c] + os[c]) * inv);
  }
}

// ---------------- stage: residual add + LayerNorm (wave-per-row) -----------
__device__ __forceinline__ void dev_add_ln(const float* __restrict__ x_in,
    const float* __restrict__ delta, const float* __restrict__ gamma,
    const float* __restrict__ beta, float* __restrict__ x_f,
    unsigned short* __restrict__ x_b) {
  int w = threadIdx.x >> 6, lane = threadIdx.x & 63;
  int c = lane * 8;
#pragma unroll
  for (int it = 0; it < 4; ++it) {
    int row = blockIdx.x * 32 + it * 8 + w;   // 256*32 = 8192 exact
    long base = (long)row * DMODEL;
    float4 v0 = *(const float4*)(x_in + base + c);
    float4 v1 = *(const float4*)(x_in + base + c + 4);
    float4 d0 = *(const float4*)(delta + base + c);
    float4 d1 = *(const float4*)(delta + base + c + 4);
    float e[8] = {v0.x + d0.x, v0.y + d0.y, v0.z + d0.z, v0.w + d0.w,
                  v1.x + d1.x, v1.y + d1.y, v1.z + d1.z, v1.w + d1.w};
    float s = 0.f, sq = 0.f;
#pragma unroll
    for (int k = 0; k < 8; ++k) { s += e[k]; sq += e[k] * e[k]; }
#pragma unroll
    for (int off = 1; off < 64; off <<= 1) {
      s += __shfl_xor(s, off, 64);
      sq += __shfl_xor(sq, off, 64);
    }
    float mean = s * (1.0f / 512.0f);
    float var = sq * (1.0f / 512.0f) - mean * mean;
    float rstd = rsqrtf(var + 1e-5f);
    float of[8]; unsigned short ob[8];
#pragma unroll
    for (int k = 0; k < 8; ++k) {
      float o = (e[k] - mean) * rstd * gamma[c + k] + beta[c + k];
      of[k] = o; ob[k] = f2bf(o);
    }
    *(float4*)(x_f + base + c) = make_float4(of[0], of[1], of[2], of[3]);
    *(float4*)(x_f + base + c + 4) = make_float4(of[4], of[5], of[6], of[7]);
    *(ushort4*)(x_b + base + c) = make_ushort4(ob[0], ob[1], ob[2], ob[3]);
    *(ushort4*)(x_b + base + c + 4) = make_ushort4(ob[4], ob[5], ob[6], ob[7]);
  }
}

// ---------------- the megakernel -------------------------------------------
__global__ __launch_bounds__(NTHREADS, 2) void mega_kernel(MegaParams P) {
  __shared__ __attribute__((aligned(128))) char sh[SH_BYTES];
  cg::grid_group grid = cg::this_grid();

  dev_converts(P);
  dev_seg_mean(P);
  grid.sync();

  for (int i = 0; i < 2; ++i) {
    // qkv = x @ Wqkv[i]^T + bqkv[i]  [8192,1536] f32
    dev_gemm(sh, P.x_b, P.wqkv_b + (long)i * 1536 * 512, P.bqkv + i * 1536,
             P.qkv_f, nullptr, 512, 1536, 1536, 0, 32, 6);
    grid.sync();
    dev_attn(sh, P.qkv_f, P.o_b);
    grid.sync();
    // o @ Wo[i]^T + bo[i] -> tmp
    dev_gemm(sh, P.o_b, P.wo_b + (long)i * 512 * 512, P.bo + i * 512,
             P.tmp_f, nullptr, 512, 512, 512, 0, 32, 2);
    grid.sync();
    dev_add_ln(P.x_f, P.tmp_f, P.ln1s + i * 512, P.ln1b + i * 512, P.x_f, P.x_b);
    grid.sync();
    // h = relu(x @ W1[i]^T + b1[i])  bf16
    dev_gemm(sh, P.x_b, P.w1_b + (long)i * 1024 * 512, P.b1 + i * 1024,
             nullptr, P.h_b, 512, 1024, 1024, 1, 32, 4);
    grid.sync();
    // y = h @ W2[i]^T + b2[i] -> tmp
    dev_gemm(sh, P.h_b, P.w2_b + (long)i * 512 * 1024, P.b2 + i * 512,
             P.tmp_f, nullptr, 1024, 512, 512, 0, 32, 2);
    grid.sync();
    dev_add_ln(P.x_f, P.tmp_f, P.ln2s + i * 512, P.ln2b + i * 512, P.x_f, P.x_b);
    grid.sync();
  }

  // out = x @ Wout^T + bout  [8192, 10000] f32
  dev_gemm(sh, P.x_b, P.wout_b, P.bout, P.out, nullptr, 512, NTYPES, NTYPES, 0, 32, 40);
}

extern "C" void kernel_launch(void* const* d_in, const int* in_sizes, int n_in,
                              void* d_out, int out_size, void* d_ws, size_t ws_size,
                              hipStream_t stream) {
  char* ws = (char*)d_ws;
  size_t off = 0;
  auto alloc = [&](size_t bytes) {
    void* p = ws + off;
    off += (bytes + 255) & ~(size_t)255;
    return p;
  };

  MegaParams P;
  P.item_ids = (const int*)d_in[0];
  P.seg_ids  = (const int*)d_in[1];
  // d_in[2] pad_mask (all false), d_in[3] future_mask (causal), d_in[4] max_len
  P.emb  = (const float*)d_in[5];
  P.Wqkv = (const float*)d_in[6];
  P.bqkv = (const float*)d_in[7];
  P.Wo   = (const float*)d_in[8];
  P.bo   = (const float*)d_in[9];
  P.W1   = (const float*)d_in[10];
  P.b1   = (const float*)d_in[11];
  P.W2   = (const float*)d_in[12];
  P.b2   = (const float*)d_in[13];
  P.ln1s = (const float*)d_in[14];
  P.ln1b = (const float*)d_in[15];
  P.ln2s = (const float*)d_in[16];
  P.ln2b = (const float*)d_in[17];
  P.Wout = (const float*)d_in[18];
  P.bout = (const float*)d_in[19];
  P.out  = (float*)d_out;

  P.x_f    = (float*)alloc((size_t)ROWS * 512 * 4);
  P.x_b    = (unsigned short*)alloc((size_t)ROWS * 512 * 2);
  P.qkv_f  = (float*)alloc((size_t)ROWS * 1536 * 4);
  P.o_b    = (unsigned short*)alloc((size_t)ROWS * 512 * 2);
  P.tmp_f  = (float*)alloc((size_t)ROWS * 512 * 4);
  P.h_b    = (unsigned short*)alloc((size_t)ROWS * 1024 * 2);
  P.wqkv_b = (unsigned short*)alloc((size_t)2 * 1536 * 512 * 2);
  P.wo_b   = (unsigned short*)alloc((size_t)2 * 512 * 512 * 2);
  P.w1_b   = (unsigned short*)alloc((size_t)2 * 1024 * 512 * 2);
  P.w2_b   = (unsigned short*)alloc((size_t)2 * 512 * 1024 * 2);
  P.wout_b = (unsigned short*)alloc((size_t)NOUT_PAD * 512 * 2);

  void* args[] = {(void*)&P};
  hipLaunchCooperativeKernel((void*)mega_kernel, dim3(NBLOCKS), dim3(NTHREADS),
                             args, 0, stream);
}

// Round 4
// 899.398 us; speedup vs baseline: 1.8003x; 1.8003x over previous
//
#include <hip/hip_runtime.h>

#define T_TOTAL 65536
#define SEQ 128
#define DMODEL 512
#define DHEAD 64
#define NTYPES 10000
#define ROWS 8192
#define NOUT_PAD 10240  // 40*256

typedef float floatx4 __attribute__((ext_vector_type(4)));
typedef short shortx8 __attribute__((ext_vector_type(8)));

#define GLOAD_LDS(gp, lp) __builtin_amdgcn_global_load_lds( \
    (const __attribute__((address_space(1))) void*)(gp),    \
    (__attribute__((address_space(3))) void*)(lp), 16, 0, 0)

#define MFMA_BF16 __builtin_amdgcn_mfma_f32_16x16x32_bf16

__device__ __forceinline__ unsigned short f2bf(float f) {
  union { float f; unsigned u; } v; v.f = f;
  unsigned u = v.u + 0x7fffu + ((v.u >> 16) & 1u);
  return (unsigned short)(u >> 16);
}

__device__ __forceinline__ void phase_barrier() {
  __builtin_amdgcn_sched_barrier(0);
  __builtin_amdgcn_s_barrier();
  __builtin_amdgcn_sched_barrier(0);
}

// ---------------- fused f32 -> bf16 weight converts (one dispatch) ---------
__global__ __launch_bounds__(256) void convert_all_kernel(
    const float* __restrict__ Wqkv, const float* __restrict__ Wo,
    const float* __restrict__ W1, const float* __restrict__ W2,
    const float* __restrict__ Wout,
    unsigned short* __restrict__ wqkv_b, unsigned short* __restrict__ wo_b,
    unsigned short* __restrict__ w1_b, unsigned short* __restrict__ w2_b,
    unsigned short* __restrict__ wout_b) {
  const long Q0 = 1572864L / 4;           // Wqkv
  const long Q1 = Q0 + 524288L / 4;       // Wo
  const long Q2 = Q1 + 1048576L / 4;      // W1
  const long Q3 = Q2 + 1048576L / 4;      // W2
  const long Q4 = Q3 + 5242880L / 4;      // Wout (padded dst)
  const long stride = 2048L * 256;
  for (long q = (long)blockIdx.x * 256 + threadIdx.x; q < Q4; q += stride) {
    const float* src; unsigned short* dst; long i; bool guard = false;
    if (q < Q0)      { src = Wqkv; dst = wqkv_b; i = q; }
    else if (q < Q1) { src = Wo;   dst = wo_b;   i = q - Q0; }
    else if (q < Q2) { src = W1;   dst = w1_b;   i = q - Q1; }
    else if (q < Q3) { src = W2;   dst = w2_b;   i = q - Q2; }
    else             { src = Wout; dst = wout_b; i = q - Q3; guard = true; }
    long e = i * 4;
    float4 v = make_float4(0.f, 0.f, 0.f, 0.f);
    if (!guard || e < 5120000L) v = *(const float4*)(src + e);
    ushort4 o;
    o.x = f2bf(v.x); o.y = f2bf(v.y); o.z = f2bf(v.z); o.w = f2bf(v.w);
    *(ushort4*)(dst + e) = o;
  }
}

// ---------------- segment-mean embedding + positional encoding -------------
__global__ __launch_bounds__(128) void seg_mean_kernel(
    const int* __restrict__ item_ids, const int* __restrict__ seg_ids,
    const float* __restrict__ emb, float* __restrict__ x_f,
    unsigned short* __restrict__ x_b) {
  int s = blockIdx.x;  // segment id = b*SEQ + l
  int lo = 0, hi = T_TOTAL;
  while (lo < hi) { int mid = (lo + hi) >> 1; if (seg_ids[mid] < s) lo = mid + 1; else hi = mid; }
  int start = lo;
  hi = T_TOTAL;
  while (lo < hi) { int mid = (lo + hi) >> 1; if (seg_ids[mid] <= s) lo = mid + 1; else hi = mid; }
  int end = lo;
  int c = threadIdx.x << 2;
  float4 acc = make_float4(0.f, 0.f, 0.f, 0.f);
  for (int j = start; j < end; ++j) {
    const float* e = emb + (long)item_ids[j] * DMODEL + c;
    float4 v = *(const float4*)e;
    acc.x += v.x; acc.y += v.y; acc.z += v.z; acc.w += v.w;
  }
  int cnt = end - start;
  float inv = cnt > 0 ? 1.0f / (float)cnt : 0.0f;
  float mv[4] = {acc.x * inv, acc.y * inv, acc.z * inv, acc.w * inv};
  int l = s & (SEQ - 1);
  const float klog = 0.017988946039015984f;  // ln(10000)/512
  long base = (long)s * DMODEL + c;
#pragma unroll
  for (int t = 0; t < 4; ++t) {
    int col = c + t;
    float den = expf(-(float)(col & ~1) * klog);
    float ang = (float)l * den;
    float pe = (col & 1) ? cosf(ang) : sinf(ang);
    float val = mv[t] + pe;
    x_f[base + t] = val;
    x_b[base + t] = f2bf(val);
  }
}

// ---------------- 128x128 bf16 MFMA GEMM (proven m97 structure) ------------
__global__ __launch_bounds__(256) void gemm_bt_kernel(
    const unsigned short* __restrict__ A,   // [M,K] bf16 row-major
    const unsigned short* __restrict__ B,   // [Npad,K] bf16 row-major
    const float* __restrict__ bias,         // [Nreal] or nullptr
    float* __restrict__ Cf,                 // [M,ldC] f32 or nullptr
    unsigned short* __restrict__ Cb,        // [M,ldC] bf16 or nullptr
    int K, int Nreal, int ldC, int relu) {
  __shared__ unsigned short As[128 * 32];
  __shared__ unsigned short Bs[128 * 32];
  const int tid = threadIdx.x;
  const int lane = tid & 63;
  const int wave = tid >> 6;
  const int wm = (wave >> 1) << 6;
  const int wn = (wave & 1) << 6;
  const int l16 = lane & 15;
  const int quad = lane >> 4;
  const long rowA0 = (long)blockIdx.x * 128;
  const long rowB0 = (long)blockIdx.y * 128;

  floatx4 acc[4][4] = {};

  const int rowOff = tid >> 2;        // 0..63
  const int kOff = (tid & 3) << 3;    // 0,8,16,24 (elements)
  const unsigned short* gA = A + (rowA0 + rowOff) * (long)K + kOff;
  const unsigned short* gB = B + (rowB0 + rowOff) * (long)K + kOff;
  unsigned short* lA = As + tid * 8;  // byte offset tid*16
  unsigned short* lB = Bs + tid * 8;

  for (int k0 = 0; k0 < K; k0 += 32) {
    __syncthreads();
    GLOAD_LDS(gA + k0, lA);
    GLOAD_LDS(gA + 64 * (long)K + k0, lA + 2048);
    GLOAD_LDS(gB + k0, lB);
    GLOAD_LDS(gB + 64 * (long)K + k0, lB + 2048);
    __syncthreads();
    shortx8 af[4], bfr[4];
#pragma unroll
    for (int i = 0; i < 4; ++i)
      af[i] = *(const shortx8*)(As + (wm + i * 16 + l16) * 32 + quad * 8);
#pragma unroll
    for (int j = 0; j < 4; ++j)
      bfr[j] = *(const shortx8*)(Bs + (wn + j * 16 + l16) * 32 + quad * 8);
#pragma unroll
    for (int i = 0; i < 4; ++i)
#pragma unroll
      for (int j = 0; j < 4; ++j)
        acc[i][j] = MFMA_BF16(af[i], bfr[j], acc[i][j], 0, 0, 0);
  }

#pragma unroll
  for (int i = 0; i < 4; ++i) {
    int row = (int)rowA0 + wm + i * 16 + quad * 4;
#pragma unroll
    for (int j = 0; j < 4; ++j) {
      int col = (int)rowB0 + wn + j * 16 + l16;
      if (col < Nreal) {
        float bv = bias ? bias[col] : 0.0f;
#pragma unroll
        for (int r = 0; r < 4; ++r) {
          float v = acc[i][j][r] + bv;
          if (relu) v = fmaxf(v, 0.0f);
          long off = (long)(row + r) * ldC + col;
          if (Cf) Cf[off] = v;
          if (Cb) Cb[off] = f2bf(v);
        }
      }
    }
  }
}

// ---------------- 256x256 8-wave 4-phase bf16 GEMM + T2 swizzle ------------
// T2 both-sides swizzle (rule 21): LDS dest stays linear (global_load_lds),
// the global SOURCE column is inverse-swizzled, and ds_read applies the same
// involution: physical chunk s of row R holds true chunk s ^ (R&7).
// Post-swizzle fragment reads hit the 1024B/128B structural minimum (no
// 16-way conflict: was 4.6e7 SQ_LDS_BANK_CONFLICT in round-3 profile).
__device__ __forceinline__ void frag_read(const unsigned short* __restrict__ base,
                                          int R, int quad, shortx8& f0, shortx8& f1) {
  int pc = quad ^ (R & 7);
  const unsigned short* p = base + R * 64;
  f0 = *(const shortx8*)(p + pc * 8);          // true chunk = quad
  f1 = *(const shortx8*)(p + (pc ^ 4) * 8);    // true chunk = quad+4
}

__global__ __launch_bounds__(512, 2) void gemm256_kernel(
    const unsigned short* __restrict__ A,   // [M,K] bf16 row-major
    const unsigned short* __restrict__ B,   // [Npad,K] bf16 row-major
    const float* __restrict__ bias,         // [Nreal] or nullptr
    float* __restrict__ Cf,                 // [M,ldC] f32 or nullptr
    unsigned short* __restrict__ Cb,        // [M,ldC] bf16 or nullptr
    int K, int Nreal, int ldC, int relu) {
  __shared__ unsigned short As[2][256 * 64];
  __shared__ unsigned short Bs[2][256 * 64];
  const int tid = threadIdx.x;
  const int lane = tid & 63;
  const int wave = tid >> 6;       // 0..7
  const int wm = wave >> 2;        // 0..1 : row half (128 rows)
  const int wn = wave & 3;         // 0..3 : col quarter (64 cols)
  const int l16 = lane & 15;
  const int quad = lane >> 4;
  const long rowA0 = (long)blockIdx.x * 256;
  const long rowB0 = (long)blockIdx.y * 256;

  floatx4 acc[8][4] = {};

  // staging: thread tid writes physical (row=tid>>3, chunk=tid&7) of a 64-row
  // issue block; source column chunk is (tid&7) ^ ((tid>>3)&7)  [T2 inverse]
  const int srow = tid >> 3;
  const int scol = (((tid & 7) ^ ((tid >> 3) & 7)) << 3);
  const unsigned short* gA = A + (rowA0 + srow) * (long)K + scol;
  const unsigned short* gB = B + (rowB0 + srow) * (long)K + scol;
  const int loff = tid * 8;
  const long rstep = 64 * (long)K;    // 64 rows; (R+64)&7 == R&7 so swizzle holds

  // prologue: K-tile 0 into buffer 0
#pragma unroll
  for (int is = 0; is < 4; ++is) {
    GLOAD_LDS(gA + is * rstep, &As[0][is * 4096 + loff]);
    GLOAD_LDS(gB + is * rstep, &Bs[0][is * 4096 + loff]);
  }
  asm volatile("s_waitcnt vmcnt(0)" ::: "memory");
  phase_barrier();

  const int KT = K >> 6;
  for (int kt = 0; kt < KT; ++kt) {
    const int cur = kt & 1;
    const unsigned short* Ab = As[cur];
    const unsigned short* Bb = Bs[cur];
    unsigned short* An = As[cur ^ 1];
    unsigned short* Bn = Bs[cur ^ 1];
    const bool stage = (kt + 1) < KT;
    const unsigned short* gAn = gA + (long)(kt + 1) * 64;
    const unsigned short* gBn = gB + (long)(kt + 1) * 64;

    shortx8 af[4][2], bf[4][2];

    // ---- phase 0: read af(m0-3)+bf(n0-1); stage ALL next-A ----
#pragma unroll
    for (int m = 0; m < 4; ++m)
      frag_read(Ab, wm * 128 + m * 16 + l16, quad, af[m][0], af[m][1]);
#pragma unroll
    for (int n = 0; n < 2; ++n)
      frag_read(Bb, wn * 64 + n * 16 + l16, quad, bf[n][0], bf[n][1]);
    if (stage) {
      GLOAD_LDS(gAn, An + loff);
      GLOAD_LDS(gAn + rstep, An + 4096 + loff);
      GLOAD_LDS(gAn + 2 * rstep, An + 8192 + loff);
      GLOAD_LDS(gAn + 3 * rstep, An + 12288 + loff);
    }
    phase_barrier();
    __builtin_amdgcn_s_setprio(1);
#pragma unroll
    for (int m = 0; m < 4; ++m)
#pragma unroll
      for (int n = 0; n < 2; ++n) {
        acc[m][n] = MFMA_BF16(af[m][0], bf[n][0], acc[m][n], 0, 0, 0);
        acc[m][n] = MFMA_BF16(af[m][1], bf[n][1], acc[m][n], 0, 0, 0);
      }
    __builtin_amdgcn_s_setprio(0);
    phase_barrier();

    // ---- phase 1: read bf(n2-3); stage ALL next-B ----
#pragma unroll
    for (int n = 2; n < 4; ++n)
      frag_read(Bb, wn * 64 + n * 16 + l16, quad, bf[n][0], bf[n][1]);
    if (stage) {
      GLOAD_LDS(gBn, Bn + loff);
      GLOAD_LDS(gBn + rstep, Bn + 4096 + loff);
      GLOAD_LDS(gBn + 2 * rstep, Bn + 8192 + loff);
      GLOAD_LDS(gBn + 3 * rstep, Bn + 12288 + loff);
    }
    phase_barrier();
    __builtin_amdgcn_s_setprio(1);
#pragma unroll
    for (int m = 0; m < 4; ++m)
#pragma unroll
      for (int n = 2; n < 4; ++n) {
        acc[m][n] = MFMA_BF16(af[m][0], bf[n][0], acc[m][n], 0, 0, 0);
        acc[m][n] = MFMA_BF16(af[m][1], bf[n][1], acc[m][n], 0, 0, 0);
      }
    __builtin_amdgcn_s_setprio(0);
    phase_barrier();

    // ---- phase 2: read af(m4-7); MFMA m4-7 x n0-1 ----
#pragma unroll
    for (int m = 0; m < 4; ++m)
      frag_read(Ab, wm * 128 + 64 + m * 16 + l16, quad, af[m][0], af[m][1]);
    phase_barrier();
    __builtin_amdgcn_s_setprio(1);
#pragma unroll
    for (int m = 0; m < 4; ++m)
#pragma unroll
      for (int n = 0; n < 2; ++n) {
        acc[4 + m][n] = MFMA_BF16(af[m][0], bf[n][0], acc[4 + m][n], 0, 0, 0);
        acc[4 + m][n] = MFMA_BF16(af[m][1], bf[n][1], acc[4 + m][n], 0, 0, 0);
      }
    __builtin_amdgcn_s_setprio(0);
    phase_barrier();

    // ---- phase 3: MFMA m4-7 x n2-3; tile-end counted drain ----
    __builtin_amdgcn_s_setprio(1);
#pragma unroll
    for (int m = 0; m < 4; ++m)
#pragma unroll
      for (int n = 2; n < 4; ++n) {
        acc[4 + m][n] = MFMA_BF16(af[m][0], bf[n][0], acc[4 + m][n], 0, 0, 0);
        acc[4 + m][n] = MFMA_BF16(af[m][1], bf[n][1], acc[4 + m][n], 0, 0, 0);
      }
    __builtin_amdgcn_s_setprio(0);
    asm volatile("s_waitcnt vmcnt(0)" ::: "memory");
    phase_barrier();
  }

  // epilogue (registers only)
#pragma unroll
  for (int m = 0; m < 8; ++m) {
    int row = (int)rowA0 + wm * 128 + m * 16 + quad * 4;
#pragma unroll
    for (int n = 0; n < 4; ++n) {
      int col = (int)rowB0 + wn * 64 + n * 16 + l16;
      if (col < Nreal) {
        float bv = bias ? bias[col] : 0.0f;
#pragma unroll
        for (int r = 0; r < 4; ++r) {
          float v = acc[m][n][r] + bv;
          if (relu) v = fmaxf(v, 0.0f);
          long off = (long)(row + r) * ldC + col;
          if (Cf) Cf[off] = v;
          if (Cb) Cb[off] = f2bf(v);
        }
      }
    }
  }
}

// ---------------- attention: one block per (b,h), parity-split j-loop ------
__global__ __launch_bounds__(256) void attn_kernel(
    const float* __restrict__ qkv,          // [ROWS, 1536]
    unsigned short* __restrict__ o_b) {     // [ROWS, 512] bf16
  __shared__ float Ks[SEQ * DHEAD];
  __shared__ float Vs[SEQ * DHEAD];
  __shared__ float Ds[SEQ];
  int b = blockIdx.x >> 3, h = blockIdx.x & 7;
  const float* base = qkv + (long)b * SEQ * 1536;
  int hoff = h * DHEAD;
  for (int idx4 = threadIdx.x; idx4 < SEQ * DHEAD / 4; idx4 += 256) {
    int l = idx4 >> 4;               // 16 float4 per 64-float row
    int c4 = (idx4 & 15) << 2;
    *(float4*)(Ks + l * 64 + c4) = *(const float4*)(base + l * 1536 + 512 + hoff + c4);
    *(float4*)(Vs + l * 64 + c4) = *(const float4*)(base + l * 1536 + 1024 + hoff + c4);
  }
  __syncthreads();
  int l = threadIdx.x & 127;
  int half = threadIdx.x >> 7;
  float q[DHEAD];
#pragma unroll
  for (int c4 = 0; c4 < 16; ++c4)
    *(float4*)(q + c4 * 4) = *(const float4*)(base + l * 1536 + hoff + c4 * 4);
  float o[DHEAD];
#pragma unroll
  for (int c = 0; c < DHEAD; ++c) o[c] = 0.f;
  float denom = 0.f;
  for (int j = half; j <= l; j += 2) {  // causal; parity split balances halves
    const float* kr = Ks + j * DHEAD;
    float s0 = 0.f, s1 = 0.f, s2 = 0.f, s3 = 0.f;
#pragma unroll
    for (int c = 0; c < DHEAD; c += 4) {
      s0 += q[c] * kr[c];         s1 += q[c + 1] * kr[c + 1];
      s2 += q[c + 2] * kr[c + 2]; s3 += q[c + 3] * kr[c + 3];
    }
    float p = __expf(((s0 + s1) + (s2 + s3)) * 0.125f);  // scale = 1/sqrt(64)
    denom += p;
    const float* vr = Vs + j * DHEAD;
#pragma unroll
    for (int c = 0; c < DHEAD; ++c) o[c] += p * vr[c];
  }
  __syncthreads();            // K no longer needed; reuse Ks for partials
  if (half) {
    float* os = Ks + l * DHEAD;
#pragma unroll
    for (int c = 0; c < DHEAD; ++c) os[c] = o[c];
    Ds[l] = denom;
  }
  __syncthreads();
  if (!half) {
    float dtot = denom + Ds[l];
    float inv = 1.0f / dtot;
    const float* os = Ks + l * DHEAD;
    unsigned short* dst = o_b + ((long)b * SEQ + l) * DMODEL + hoff;
#pragma unroll
    for (int c0 = 0; c0 < DHEAD; c0 += 8) {
      shortx8 ov;
#pragma unroll
      for (int k = 0; k < 8; ++k)
        ov[k] = (short)f2bf((o[c0 + k] + os[c0 + k]) * inv);
      *(shortx8*)(dst + c0) = ov;
    }
  }
}

// ---------------- residual add + LayerNorm, writes f32 + bf16 --------------
__global__ __launch_bounds__(256) void add_ln_kernel(
    const float* __restrict__ x_in, const float* __restrict__ delta,
    const float* __restrict__ gamma, const float* __restrict__ beta,
    float* __restrict__ x_f, unsigned short* __restrict__ x_b) {
  int row = blockIdx.x;
  int tid = threadIdx.x;
  long base = (long)row * DMODEL;
  int c = tid * 2;
  float2 xv = *(const float2*)(x_in + base + c);
  float2 dv = *(const float2*)(delta + base + c);
  float a = xv.x + dv.x, b = xv.y + dv.y;
  float s = a + b;
  float sq = a * a + b * b;
#pragma unroll
  for (int off = 32; off > 0; off >>= 1) {
    s += __shfl_down(s, off, 64);
    sq += __shfl_down(sq, off, 64);
  }
  __shared__ float red[8];
  __shared__ float mean_s, rstd_s;
  int wv = tid >> 6, ln = tid & 63;
  if (ln == 0) { red[wv] = s; red[4 + wv] = sq; }
  __syncthreads();
  if (tid == 0) {
    float S = red[0] + red[1] + red[2] + red[3];
    float SQ = red[4] + red[5] + red[6] + red[7];
    float mean = S * (1.0f / 512.0f);
    float var = SQ * (1.0f / 512.0f) - mean * mean;
    mean_s = mean;
    rstd_s = rsqrtf(var + 1e-5f);
  }
  __syncthreads();
  float mean = mean_s, rstd = rstd_s;
  float o0 = (a - mean) * rstd * gamma[c] + beta[c];
  float o1 = (b - mean) * rstd * gamma[c + 1] + beta[c + 1];
  x_f[base + c] = o0;
  x_f[base + c + 1] = o1;
  x_b[base + c] = f2bf(o0);
  x_b[base + c + 1] = f2bf(o1);
}

extern "C" void kernel_launch(void* const* d_in, const int* in_sizes, int n_in,
                              void* d_out, int out_size, void* d_ws, size_t ws_size,
                              hipStream_t stream) {
  const int* item_ids = (const int*)d_in[0];
  const int* seg_ids = (const int*)d_in[1];
  // d_in[2] pad_mask: all-false; d_in[3] future_mask: causal; d_in[4] max_len.
  const float* emb  = (const float*)d_in[5];
  const float* Wqkv = (const float*)d_in[6];
  const float* bqkv = (const float*)d_in[7];
  const float* Wo   = (const float*)d_in[8];
  const float* bo   = (const float*)d_in[9];
  const float* W1   = (const float*)d_in[10];
  const float* b1   = (const float*)d_in[11];
  const float* W2   = (const float*)d_in[12];
  const float* b2   = (const float*)d_in[13];
  const float* ln1s = (const float*)d_in[14];
  const float* ln1b = (const float*)d_in[15];
  const float* ln2s = (const float*)d_in[16];
  const float* ln2b = (const float*)d_in[17];
  const float* Wout = (const float*)d_in[18];
  const float* bout = (const float*)d_in[19];
  float* out = (float*)d_out;

  char* ws = (char*)d_ws;
  size_t off = 0;
  auto alloc = [&](size_t bytes) {
    void* p = ws + off;
    off += (bytes + 255) & ~(size_t)255;
    return p;
  };
  float* x_f  = (float*)alloc((size_t)ROWS * 512 * 4);
  unsigned short* x_b = (unsigned short*)alloc((size_t)ROWS * 512 * 2);
  float* qkv_f = (float*)alloc((size_t)ROWS * 1536 * 4);
  unsigned short* o_b = (unsigned short*)alloc((size_t)ROWS * 512 * 2);
  float* tmp_f = (float*)alloc((size_t)ROWS * 512 * 4);
  unsigned short* h_b = (unsigned short*)alloc((size_t)ROWS * 1024 * 2);
  unsigned short* wqkv_b = (unsigned short*)alloc((size_t)2 * 1536 * 512 * 2);
  unsigned short* wo_b = (unsigned short*)alloc((size_t)2 * 512 * 512 * 2);
  unsigned short* w1_b = (unsigned short*)alloc((size_t)2 * 1024 * 512 * 2);
  unsigned short* w2_b = (unsigned short*)alloc((size_t)2 * 512 * 1024 * 2);
  unsigned short* wout_b = (unsigned short*)alloc((size_t)NOUT_PAD * 512 * 2);

  convert_all_kernel<<<2048, 256, 0, stream>>>(
      Wqkv, Wo, W1, W2, Wout, wqkv_b, wo_b, w1_b, w2_b, wout_b);

  seg_mean_kernel<<<ROWS, 128, 0, stream>>>(item_ids, seg_ids, emb, x_f, x_b);

  for (int i = 0; i < 2; ++i) {
    // qkv = x @ Wqkv[i]^T + bqkv[i]   [8192,1536] f32  (256^2 swz kernel)
    gemm256_kernel<<<dim3(32, 6), 512, 0, stream>>>(
        x_b, wqkv_b + (long)i * 1536 * 512, bqkv + i * 1536,
        qkv_f, nullptr, 512, 1536, 1536, 0);
    attn_kernel<<<512, 256, 0, stream>>>(qkv_f, o_b);
    // o @ Wo[i]^T + bo[i] -> tmp
    gemm_bt_kernel<<<dim3(64, 4), 256, 0, stream>>>(
        o_b, wo_b + (long)i * 512 * 512, bo + i * 512,
        tmp_f, nullptr, 512, 512, 512, 0);
    add_ln_kernel<<<ROWS, 256, 0, stream>>>(x_f, tmp_f, ln1s + i * 512, ln1b + i * 512, x_f, x_b);
    // h = relu(x @ W1[i]^T + b1[i])  bf16 only
    gemm_bt_kernel<<<dim3(64, 8), 256, 0, stream>>>(
        x_b, w1_b + (long)i * 1024 * 512, b1 + i * 1024,
        nullptr, h_b, 512, 1024, 1024, 1);
    // y = h @ W2[i]^T + b2[i] -> tmp
    gemm_bt_kernel<<<dim3(64, 4), 256, 0, stream>>>(
        h_b, w2_b + (long)i * 512 * 1024, b2 + i * 512,
        tmp_f, nullptr, 1024, 512, 512, 0);
    add_ln_kernel<<<ROWS, 256, 0, stream>>>(x_f, tmp_f, ln2s + i * 512, ln2b + i * 512, x_f, x_b);
  }

  // out = x @ Wout^T + bout   [8192, 10000] f32  (256^2 swz kernel)
  gemm256_kernel<<<dim3(32, 40), 512, 0, stream>>>(
      x_b, wout_b, bout, out, nullptr, 512, NTYPES, NTYPES, 0);
}